// Round 3
// baseline (380.368 us; speedup 1.0000x reference)
//
#include <hip/hip_runtime.h>
#include <cstdint>
#include <cstddef>

#define B_ 4
#define T_ 2048
#define C_ 768
#define H_ 12
#define D_ 64
#define M_ (B_*T_)      // 8192
#define C3_ 2304
#define HID_ 3072

typedef unsigned short ushort_t;
typedef __bf16 bf16x8_t __attribute__((ext_vector_type(8)));
typedef float f32x4 __attribute__((ext_vector_type(4)));

typedef const __attribute__((address_space(1))) void* gas_ptr;
typedef __attribute__((address_space(3))) void* las_ptr;

__device__ __forceinline__ void gload_lds16(const ushort_t* g, ushort_t* l) {
  // async global->LDS, 16B per lane; LDS dest = wave-uniform base + lane*16
  __builtin_amdgcn_global_load_lds((gas_ptr)g, (las_ptr)l, 16, 0, 0);
}

__device__ __forceinline__ float bf2f(ushort_t h) {
  union { unsigned int u; float f; } cv; cv.u = ((unsigned int)h) << 16; return cv.f;
}
__device__ __forceinline__ ushort_t f2bf(float f) {
  union { float f; unsigned int u; } cv; cv.f = f;
  unsigned int u = cv.u;
  unsigned int r = (u + 0x7FFFu + ((u >> 16) & 1u)) >> 16;
  return (ushort_t)r;
}
__device__ __forceinline__ ushort_t f2bf_trunc(float f) {   // RTZ: 1 op; fine for P in (0,1]
  union { float f; unsigned int u; } cv; cv.f = f;
  return (ushort_t)(cv.u >> 16);
}

// ---------------- transpose+cast W[K,N] f32 -> Wt[N,K] bf16 ----------------
__global__ __launch_bounds__(256) void transpose_k(const float* __restrict__ in,
                                                   ushort_t* __restrict__ out, int K, int N) {
  __shared__ ushort_t tile[32][33];
  int nx = threadIdx.x, ky = threadIdx.y;           // block (32,8)
  int n0 = blockIdx.x * 32, k0 = blockIdx.y * 32;
#pragma unroll
  for (int i = 0; i < 4; i++)
    tile[ky + i * 8][nx] = f2bf(in[(size_t)(k0 + ky + i * 8) * N + n0 + nx]);
  __syncthreads();
#pragma unroll
  for (int i = 0; i < 4; i++)
    out[(size_t)(n0 + ky + i * 8) * K + k0 + nx] = tile[nx][ky + i * 8];
}

// ---------------- V transpose: qkv V-part [t][d] -> Vg[bh][d][t] ----------------
__global__ __launch_bounds__(256) void vtrans_k(const ushort_t* __restrict__ qkv,
                                                ushort_t* __restrict__ vg) {
  __shared__ ushort_t tile[32][33];
  int nx = threadIdx.x, ky = threadIdx.y;           // block (32,8)
  int t0 = blockIdx.x * 32, d0 = blockIdx.y * 32;
  int bh = blockIdx.z;
  int b = bh / H_, h = bh % H_;
  const ushort_t* src = qkv + (size_t)b * T_ * C3_ + 2 * C_ + h * D_;
#pragma unroll
  for (int i = 0; i < 4; i++)
    tile[ky + i * 8][nx] = src[(size_t)(t0 + ky + i * 8) * C3_ + d0 + nx];
  __syncthreads();
  ushort_t* dst = vg + (size_t)bh * D_ * T_;
#pragma unroll
  for (int i = 0; i < 4; i++)
    dst[(size_t)(d0 + ky + i * 8) * T_ + t0 + nx] = tile[nx][ky + i * 8];
}

// ---------------- layernorm (row = 768), f32 in -> bf16 out ----------------
__global__ __launch_bounds__(256) void ln_k(const float* __restrict__ x, const float* __restrict__ g,
                                            const float* __restrict__ bb, ushort_t* __restrict__ out) {
  __shared__ float red[8];
  int row = blockIdx.x, t = threadIdx.x;
  const float* xr = x + (size_t)row * C_;
  float v0 = xr[t], v1 = xr[t + 256], v2 = xr[t + 512];
  float s = v0 + v1 + v2;
  float s2 = v0 * v0 + v1 * v1 + v2 * v2;
#pragma unroll
  for (int m = 32; m >= 1; m >>= 1) { s += __shfl_xor(s, m); s2 += __shfl_xor(s2, m); }
  int w = t >> 6;
  if ((t & 63) == 0) { red[w * 2] = s; red[w * 2 + 1] = s2; }
  __syncthreads();
  s = red[0] + red[2] + red[4] + red[6];
  s2 = red[1] + red[3] + red[5] + red[7];
  float mu = s * (1.f / C_);
  float var = s2 * (1.f / C_) - mu * mu;
  float rstd = rsqrtf(var + 1e-5f);
  out[(size_t)row * C_ + t]       = f2bf((v0 - mu) * rstd * g[t] + bb[t]);
  out[(size_t)row * C_ + t + 256] = f2bf((v1 - mu) * rstd * g[t + 256] + bb[t + 256]);
  out[(size_t)row * C_ + t + 512] = f2bf((v2 - mu) * rstd * g[t + 512] + bb[t + 512]);
}

// ---------------- GEMM: C[M,N] = A[M,K] @ Bt[N,K]^T, fused epilogues ----------------
// R10: software-pipelined K-loop (double-buffered LDS, counted vmcnt(4), raw
// barriers) + bijective XCD swizzle. R11: LDS bank-conflict swizzle. The old
// read As[wm+lm][q8] was an 8-way conflict (bank = 16*lm+4*q mod 32: lanes
// {lm,lm+4,lm+8,lm+12} collide) -> SQ_LDS_BANK_CONFLICT 4.7M/dispatch. Fix:
// physical 16B chunk = logical chunk ^ ((row>>1)&3), applied BOTH sides
// (rule #21): pre-swizzled GLOBAL source chunk in STAGE (linear gload_lds
// dest) + swizzled chunk on ds_read. row>>1 (not row&3) gives uniform
// 2-lanes/bank (free, m136); row&3 would still leave 4-way. Read chunk is
// lane-constant (row bits 1-2 invariant across +16i / wm).
#define MFMA16(d, a, b) d = __builtin_amdgcn_mfma_f32_16x16x32_bf16(a, b, d, 0, 0, 0)

template <int EPI>
__global__ void gemm_bt_k(const ushort_t* __restrict__ A,
                          const ushort_t* __restrict__ Bt,
                          const float* __restrict__ res,
                          void* __restrict__ outp,
                          int N, int K) {
  __shared__ __align__(16) ushort_t As[2][128][32];
  __shared__ __align__(16) ushort_t Bs[2][128][32];
  int t = threadIdx.x;

  // XCD-aware block swizzle (all launch grids are %8==0; guard anyway)
  int nwg = (int)(gridDim.x * gridDim.y);
  int orig = (int)(blockIdx.y * gridDim.x + blockIdx.x);
  int swz = (nwg & 7) ? orig : ((orig & 7) * (nwg >> 3) + (orig >> 3));
  int bx = swz % (int)gridDim.x, by = swz / (int)gridDim.x;
  int bn = bx * 128, bm = by * 128;

  int lane = t & 63, w = t >> 6;
  int wm = (w >> 1) * 64, wn = (w & 1) * 64;
  int lm = lane & 15;

  // staging: lane -> (row lr, phys chunk lane&3); source = logical chunk
  // (lane&3) ^ ((lr>>1)&3)  [lr>>1 == lane>>3]
  int lr = lane >> 2;
  int lc = (((lane & 3) ^ ((lane >> 3) & 3)) * 8);
  // read side: phys chunk = q ^ ((lm>>1)&3); lane bits 1-2 == lm bits 1-2
  int cx = (((lane >> 4) ^ ((lane >> 1) & 3)) * 8);

  const ushort_t* ga0 = A  + (size_t)(bm + w * 16 + lr) * K + lc;
  const ushort_t* gb0 = Bt + (size_t)(bn + w * 16 + lr) * K + lc;
  const size_t kstep64 = (size_t)64 * K;

  const f32x4 fz = {0.f, 0.f, 0.f, 0.f};
  f32x4 acc00 = fz, acc01 = fz, acc02 = fz, acc03 = fz;
  f32x4 acc10 = fz, acc11 = fz, acc12 = fz, acc13 = fz;
  f32x4 acc20 = fz, acc21 = fz, acc22 = fz, acc23 = fz;
  f32x4 acc30 = fz, acc31 = fz, acc32 = fz, acc33 = fz;

#define STAGE(BUF, KOFF) do {                                   \
    gload_lds16(ga0 + (KOFF), &As[BUF][w * 16][0]);             \
    gload_lds16(ga0 + kstep64 + (KOFF), &As[BUF][w * 16 + 64][0]); \
    gload_lds16(gb0 + (KOFF), &Bs[BUF][w * 16][0]);             \
    gload_lds16(gb0 + kstep64 + (KOFF), &Bs[BUF][w * 16 + 64][0]); \
  } while (0)

#define COMPUTE(BUF) do {                                            \
    bf16x8_t af0 = *(const bf16x8_t*)&As[BUF][wm + lm][cx];          \
    bf16x8_t af1 = *(const bf16x8_t*)&As[BUF][wm + 16 + lm][cx];     \
    bf16x8_t af2 = *(const bf16x8_t*)&As[BUF][wm + 32 + lm][cx];     \
    bf16x8_t af3 = *(const bf16x8_t*)&As[BUF][wm + 48 + lm][cx];     \
    bf16x8_t bg0 = *(const bf16x8_t*)&Bs[BUF][wn + lm][cx];          \
    bf16x8_t bg1 = *(const bf16x8_t*)&Bs[BUF][wn + 16 + lm][cx];     \
    bf16x8_t bg2 = *(const bf16x8_t*)&Bs[BUF][wn + 32 + lm][cx];     \
    bf16x8_t bg3 = *(const bf16x8_t*)&Bs[BUF][wn + 48 + lm][cx];     \
    MFMA16(acc00, af0, bg0); MFMA16(acc01, af0, bg1); MFMA16(acc02, af0, bg2); MFMA16(acc03, af0, bg3); \
    MFMA16(acc10, af1, bg0); MFMA16(acc11, af1, bg1); MFMA16(acc12, af1, bg2); MFMA16(acc13, af1, bg3); \
    MFMA16(acc20, af2, bg0); MFMA16(acc21, af2, bg1); MFMA16(acc22, af2, bg2); MFMA16(acc23, af2, bg3); \
    MFMA16(acc30, af3, bg0); MFMA16(acc31, af3, bg1); MFMA16(acc32, af3, bg2); MFMA16(acc33, af3, bg3); \
  } while (0)

  STAGE(0, 0);
  for (int k0 = 0; k0 < K; k0 += 64) {           // K % 64 == 0 for all shapes
    STAGE(1, k0 + 32);
    asm volatile("s_waitcnt vmcnt(4)" ::: "memory");  // buf0 landed; buf1 in flight
    __builtin_amdgcn_s_barrier();
    asm volatile("" ::: "memory");
    COMPUTE(0);
    asm volatile("" ::: "memory");
    __builtin_amdgcn_s_barrier();                // buf0 reads done -> refillable
    if (k0 + 64 < K) {
      STAGE(0, k0 + 64);
      asm volatile("s_waitcnt vmcnt(4)" ::: "memory");  // buf1 landed; buf0 in flight
    } else {
      asm volatile("s_waitcnt vmcnt(0)" ::: "memory");  // tail: drain
    }
    __builtin_amdgcn_s_barrier();
    asm volatile("" ::: "memory");
    COMPUTE(1);
    asm volatile("" ::: "memory");
    __builtin_amdgcn_s_barrier();                // buf1 reads done -> refillable
  }
#undef STAGE
#undef COMPUTE

  int rowb = bm + wm + (lane >> 4) * 4;
  int colb = bn + wn + lm;

#define ST(vv, row, jj) do { \
    float v = (vv); \
    size_t idx = (size_t)(row) * N + colb + (jj) * 16; \
    if constexpr (EPI == 0) { ((ushort_t*)outp)[idx] = f2bf(v); } \
    else if constexpr (EPI == 1) { ((float*)outp)[idx] = v + res[idx]; } \
    else { float gl = 0.5f * v * (1.0f + erff(v * 0.70710678118654752f)); \
           ((ushort_t*)outp)[idx] = f2bf(gl); } \
  } while (0)
#define STROW(a0, a1, a2, a3, row, rr) \
    ST(a0[rr], row, 0); ST(a1[rr], row, 1); ST(a2[rr], row, 2); ST(a3[rr], row, 3);
#define STBLK(a0, a1, a2, a3, rbase) \
    STROW(a0, a1, a2, a3, (rbase), 0) STROW(a0, a1, a2, a3, (rbase) + 1, 1) \
    STROW(a0, a1, a2, a3, (rbase) + 2, 2) STROW(a0, a1, a2, a3, (rbase) + 3, 3)

  STBLK(acc00, acc01, acc02, acc03, rowb)
  STBLK(acc10, acc11, acc12, acc13, rowb + 16)
  STBLK(acc20, acc21, acc22, acc23, rowb + 32)
  STBLK(acc30, acc31, acc32, acc33, rowb + 48)
#undef ST
#undef STROW
#undef STBLK
}

// ---------------- flash attention (causal) ----------------
// R9: cooperative LDS staging of K/V tiles (all 4 waves share the same tiles).
// Double-buffered global_load_lds with counted s_waitcnt vmcnt(4) + raw
// s_barrier so the next tile's loads stay in flight across the barrier.
// XOR-swizzle applied on BOTH sides (pre-swizzled global source + swizzled
// ds_read). LDS 41KB -> 3 blocks/CU.
__device__ __forceinline__ void stage64(const ushort_t* __restrict__ g, size_t strideE,
                                        ushort_t* l, int w, int lane) {
  // stage 16 rows (w*16..w*16+15) of a 64x64 bf16 tile: 2 x 1KB gload_lds
  int rl = lane >> 3;                        // local row 0..7 within 8-row slab
  int ce = ((lane & 7) ^ rl) << 3;           // pre-swizzled element col (8-elem chunks)
  const ushort_t* g0 = g + (size_t)(w * 16 + rl) * strideE + ce;
  gload_lds16(g0, l + (size_t)(w * 16) * 64);
  const ushort_t* g1 = g + (size_t)(w * 16 + 8 + rl) * strideE + ce;
  gload_lds16(g1, l + (size_t)(w * 16 + 8) * 64);
}

__global__ __launch_bounds__(256, 3) void attn_k(const ushort_t* __restrict__ qkv,
                                                 const ushort_t* __restrict__ vg,
                                                 ushort_t* __restrict__ y) {
  __shared__ __align__(16) ushort_t Ks[2][64][64];   // [buf][t_local][d] swizzled
  __shared__ __align__(16) ushort_t Vs[2][64][64];   // [buf][d][t_local] swizzled
  __shared__ __align__(16) ushort_t Ps[4][16][72];

  int t = threadIdx.x;
  int w = t >> 6, lane = t & 63;
  int lm = lane & 15, qq = lane >> 4, q8 = qq * 8;
  int bh = blockIdx.x;
  int qt = (int)gridDim.y - 1 - (int)blockIdx.y;   // heavy q-tiles dispatch first
  int b = bh / H_, h = bh % H_;

  size_t baserow = (size_t)b * T_;
  const ushort_t* qkvb = qkv + baserow * C3_ + h * D_;
  const ushort_t* kbase = qkvb + C_;
  const ushort_t* vbase = vg + (size_t)bh * D_ * T_;

  int qrow0 = qt * 64 + w * 16;   // this wave's 16 q rows
  const ushort_t* qp = qkvb + (size_t)(qrow0 + lm) * C3_ + q8;
  bf16x8_t aq0 = *(const bf16x8_t*)(qp);
  bf16x8_t aq1 = *(const bf16x8_t*)(qp + 32);
  __builtin_amdgcn_s_waitcnt(0);   // drain Q loads so in-loop vmcnt counting is exact

  const f32x4 fz = {0.f, 0.f, 0.f, 0.f};
  f32x4 aO0 = fz, aO1 = fz, aO2 = fz, aO3 = fz;
  f32x4 lsum = fz;                 // per-lane partial softmax denominators

  const float SC = 0.125f * 1.44269504088896340736f;  // scale * log2(e)

#define BODY(CUR, KT, MASKED)                                                   \
  {                                                                             \
    const char* Kb = (const char*)&Ks[CUR][0][0];                               \
    const char* Vb = (const char*)&Vs[CUR][0][0];                               \
    const int rsw = (lm & 7) << 4;                                              \
    const int c0 = (qq * 16) ^ rsw;                                             \
    const int c1 = (64 + qq * 16) ^ rsw;                                        \
    bf16x8_t kf[8], vv[8];                                                      \
    _Pragma("unroll") for (int j = 0; j < 4; j++) {                             \
      int rb = (j * 16 + lm) << 7;                                              \
      kf[2*j]   = *(const bf16x8_t*)(Kb + rb + c0);                             \
      kf[2*j+1] = *(const bf16x8_t*)(Kb + rb + c1);                             \
      vv[2*j]   = *(const bf16x8_t*)(Vb + rb + c0);                             \
      vv[2*j+1] = *(const bf16x8_t*)(Vb + rb + c1);                             \
    }                                                                           \
    f32x4 sa0 = fz, sa1 = fz, sa2 = fz, sa3 = fz;                               \
    MFMA16(sa0, aq0, kf[0]); MFMA16(sa0, aq1, kf[1]);                           \
    MFMA16(sa1, aq0, kf[2]); MFMA16(sa1, aq1, kf[3]);                           \
    MFMA16(sa2, aq0, kf[4]); MFMA16(sa2, aq1, kf[5]);                           \
    MFMA16(sa3, aq0, kf[6]); MFMA16(sa3, aq1, kf[7]);                           \
    _Pragma("unroll") for (int j = 0; j < 4; j++) {                             \
      f32x4 sj = (j == 0) ? sa0 : (j == 1) ? sa1 : (j == 2) ? sa2 : sa3;        \
      _Pragma("unroll") for (int r2 = 0; r2 < 4; r2++) {                        \
        float v = sj[r2] * SC;                                                  \
        if (MASKED && (j * 16 + lm) > (w * 16 + qq * 4 + r2)) v = -1e30f;       \
        float p = exp2f(v);                                                     \
        lsum[r2] += p;                                                          \
        Ps[w][qq * 4 + r2][j * 16 + lm] = f2bf_trunc(p);                        \
      }                                                                         \
    }                                                                           \
    {                                                                           \
      bf16x8_t ap_lo = *(const bf16x8_t*)&Ps[w][lm][q8];                        \
      bf16x8_t ap_hi = *(const bf16x8_t*)&Ps[w][lm][32 + q8];                   \
      MFMA16(aO0, ap_lo, vv[0]); MFMA16(aO0, ap_hi, vv[1]);                     \
      MFMA16(aO1, ap_lo, vv[2]); MFMA16(aO1, ap_hi, vv[3]);                     \
      MFMA16(aO2, ap_lo, vv[4]); MFMA16(aO2, ap_hi, vv[5]);                     \
      MFMA16(aO3, ap_lo, vv[6]); MFMA16(aO3, ap_hi, vv[7]);                     \
    }                                                                           \
  }

  // prologue: stage tile 0 into buffer 0 (4 async loads per wave)
  stage64(kbase, C3_, &Ks[0][0][0], w, lane);
  stage64(vbase, T_, &Vs[0][0][0], w, lane);
  int cur = 0;
  for (int kt = 0; kt <= qt; ++kt) {
    if (kt < qt) {
      // issue next tile's loads into the other buffer, keep them in flight
      stage64(kbase + (size_t)(kt + 1) * 64 * C3_, C3_, &Ks[cur ^ 1][0][0], w, lane);
      stage64(vbase + (size_t)(kt + 1) * 64,       T_,  &Vs[cur ^ 1][0][0], w, lane);
      asm volatile("s_waitcnt vmcnt(4)" ::: "memory");  // tile kt landed; kt+1 in flight
    } else {
      asm volatile("s_waitcnt vmcnt(0)" ::: "memory");  // last tile: drain
    }
    __builtin_amdgcn_s_barrier();      // all waves' tile-kt data visible
    asm volatile("" ::: "memory");     // fence: no LDS reads hoisted above barrier
    if (kt == qt) { BODY(cur, kt, true) }
    else          { BODY(cur, kt, false) }
    asm volatile("" ::: "memory");     // fence: reads done before buffer reuse
    __builtin_amdgcn_s_barrier();      // safe to overwrite buffer cur next iter
    cur ^= 1;
  }
#undef BODY

#pragma unroll
  for (int r2 = 0; r2 < 4; r2++) {
    float s = lsum[r2];
    s += __shfl_xor(s, 1);
    s += __shfl_xor(s, 2);
    s += __shfl_xor(s, 4);
    s += __shfl_xor(s, 8);
    float inv = 1.f / s;
    size_t orow = (baserow + qrow0 + qq * 4 + r2) * C_ + h * D_;
    y[orow + lm]      = f2bf(aO0[r2] * inv);
    y[orow + 16 + lm] = f2bf(aO1[r2] * inv);
    y[orow + 32 + lm] = f2bf(aO2[r2] * inv);
    y[orow + 48 + lm] = f2bf(aO3[r2] * inv);
  }
}

extern "C" void kernel_launch(void* const* d_in, const int* in_sizes, int n_in,
                              void* d_out, int out_size, void* d_ws, size_t ws_size,
                              hipStream_t stream) {
  (void)in_sizes; (void)n_in; (void)out_size; (void)ws_size;
  const float* x      = (const float*)d_in[0];
  const float* ln1_g  = (const float*)d_in[1];
  const float* ln1_b  = (const float*)d_in[2];
  const float* W_attn = (const float*)d_in[3];
  const float* W_o    = (const float*)d_in[4];
  const float* ln2_g  = (const float*)d_in[5];
  const float* ln2_b  = (const float*)d_in[6];
  const float* W_fc   = (const float*)d_in[7];
  const float* W_proj = (const float*)d_in[8];

  char* ws = (char*)d_ws;
  ushort_t* big  = (ushort_t*)(ws);
  ushort_t* Vg   = (ushort_t*)(ws + 37748736);  // V^T [48][64][2048] bf16; dead before h is written
  ushort_t* tmp  = (ushort_t*)(ws + 50331648);  // xhat1 / y / xhat2 (8192x768 bf16)
  float*    x2   = (float*)   (ws + 62914560);  // residual1 fp32 (8192x768)
  ushort_t* Wat  = (ushort_t*)(ws + 88080384);  // W_attn^T [2304,768] bf16
  ushort_t* Wot  = (ushort_t*)(ws + 91619328);  // W_o^T    [768,768]  bf16
  ushort_t* Wfct = (ushort_t*)(ws + 92798976);  // W_fc^T   [3072,768] bf16
  ushort_t* Wpt  = (ushort_t*)(ws + 97517568);  // W_proj^T [768,3072] bf16

  dim3 tb(32, 8);
  transpose_k<<<dim3(C3_ / 32, C_ / 32), tb, 0, stream>>>(W_attn, Wat, C_, C3_);
  transpose_k<<<dim3(C_ / 32, C_ / 32), tb, 0, stream>>>(W_o, Wot, C_, C_);
  transpose_k<<<dim3(HID_ / 32, C_ / 32), tb, 0, stream>>>(W_fc, Wfct, C_, HID_);
  transpose_k<<<dim3(C_ / 32, HID_ / 32), tb, 0, stream>>>(W_proj, Wpt, HID_, C_);

  ln_k<<<M_, 256, 0, stream>>>(x, ln1_g, ln1_b, tmp);
  gemm_bt_k<0><<<dim3(C3_ / 128, M_ / 128), 256, 0, stream>>>(tmp, Wat, nullptr, big, C3_, C_);
  vtrans_k<<<dim3(T_ / 32, D_ / 32, B_ * H_), tb, 0, stream>>>(big, Vg);
  attn_k<<<dim3(B_ * H_, T_ / 64), 256, 0, stream>>>(big, Vg, tmp);
  gemm_bt_k<1><<<dim3(C_ / 128, M_ / 128), 256, 0, stream>>>(tmp, Wot, x, x2, C_, C_);
  ln_k<<<M_, 256, 0, stream>>>(x2, ln2_g, ln2_b, tmp);
  gemm_bt_k<2><<<dim3(HID_ / 128, M_ / 128), 256, 0, stream>>>(tmp, Wfct, nullptr, big, HID_, C_);
  gemm_bt_k<1><<<dim3(C_ / 128, M_ / 128), 256, 0, stream>>>(big, Wpt, x2, d_out, C_, HID_);
}

// Round 4
// 379.939 us; speedup vs baseline: 1.0011x; 1.0011x over previous
//
#include <hip/hip_runtime.h>
#include <cstdint>
#include <cstddef>

#define B_ 4
#define T_ 2048
#define C_ 768
#define H_ 12
#define D_ 64
#define M_ (B_*T_)      // 8192
#define C3_ 2304
#define HID_ 3072

typedef unsigned short ushort_t;
typedef __bf16 bf16x8_t __attribute__((ext_vector_type(8)));
typedef float f32x4 __attribute__((ext_vector_type(4)));

typedef const __attribute__((address_space(1))) void* gas_ptr;
typedef __attribute__((address_space(3))) void* las_ptr;

__device__ __forceinline__ void gload_lds16(const ushort_t* g, ushort_t* l) {
  // async global->LDS, 16B per lane; LDS dest = wave-uniform base + lane*16
  __builtin_amdgcn_global_load_lds((gas_ptr)g, (las_ptr)l, 16, 0, 0);
}

__device__ __forceinline__ float bf2f(ushort_t h) {
  union { unsigned int u; float f; } cv; cv.u = ((unsigned int)h) << 16; return cv.f;
}
__device__ __forceinline__ ushort_t f2bf(float f) {
  union { float f; unsigned int u; } cv; cv.f = f;
  unsigned int u = cv.u;
  unsigned int r = (u + 0x7FFFu + ((u >> 16) & 1u)) >> 16;
  return (ushort_t)r;
}
__device__ __forceinline__ ushort_t f2bf_trunc(float f) {   // RTZ: 1 op; fine for P in (0,1]
  union { float f; unsigned int u; } cv; cv.f = f;
  return (ushort_t)(cv.u >> 16);
}

// ---------------- transpose+cast W[K,N] f32 -> Wt[N,K] bf16 ----------------
__global__ __launch_bounds__(256) void transpose_k(const float* __restrict__ in,
                                                   ushort_t* __restrict__ out, int K, int N) {
  __shared__ ushort_t tile[32][33];
  int nx = threadIdx.x, ky = threadIdx.y;           // block (32,8)
  int n0 = blockIdx.x * 32, k0 = blockIdx.y * 32;
#pragma unroll
  for (int i = 0; i < 4; i++)
    tile[ky + i * 8][nx] = f2bf(in[(size_t)(k0 + ky + i * 8) * N + n0 + nx]);
  __syncthreads();
#pragma unroll
  for (int i = 0; i < 4; i++)
    out[(size_t)(n0 + ky + i * 8) * K + k0 + nx] = tile[nx][ky + i * 8];
}

// ---------------- V transpose: qkv V-part [t][d] -> Vg[bh][d][t] ----------------
__global__ __launch_bounds__(256) void vtrans_k(const ushort_t* __restrict__ qkv,
                                                ushort_t* __restrict__ vg) {
  __shared__ ushort_t tile[32][33];
  int nx = threadIdx.x, ky = threadIdx.y;           // block (32,8)
  int t0 = blockIdx.x * 32, d0 = blockIdx.y * 32;
  int bh = blockIdx.z;
  int b = bh / H_, h = bh % H_;
  const ushort_t* src = qkv + (size_t)b * T_ * C3_ + 2 * C_ + h * D_;
#pragma unroll
  for (int i = 0; i < 4; i++)
    tile[ky + i * 8][nx] = src[(size_t)(t0 + ky + i * 8) * C3_ + d0 + nx];
  __syncthreads();
  ushort_t* dst = vg + (size_t)bh * D_ * T_;
#pragma unroll
  for (int i = 0; i < 4; i++)
    dst[(size_t)(d0 + ky + i * 8) * T_ + t0 + nx] = tile[nx][ky + i * 8];
}

// ---------------- layernorm (row = 768), f32 in -> bf16 out ----------------
__global__ __launch_bounds__(256) void ln_k(const float* __restrict__ x, const float* __restrict__ g,
                                            const float* __restrict__ bb, ushort_t* __restrict__ out) {
  __shared__ float red[8];
  int row = blockIdx.x, t = threadIdx.x;
  const float* xr = x + (size_t)row * C_;
  float v0 = xr[t], v1 = xr[t + 256], v2 = xr[t + 512];
  float s = v0 + v1 + v2;
  float s2 = v0 * v0 + v1 * v1 + v2 * v2;
#pragma unroll
  for (int m = 32; m >= 1; m >>= 1) { s += __shfl_xor(s, m); s2 += __shfl_xor(s2, m); }
  int w = t >> 6;
  if ((t & 63) == 0) { red[w * 2] = s; red[w * 2 + 1] = s2; }
  __syncthreads();
  s = red[0] + red[2] + red[4] + red[6];
  s2 = red[1] + red[3] + red[5] + red[7];
  float mu = s * (1.f / C_);
  float var = s2 * (1.f / C_) - mu * mu;
  float rstd = rsqrtf(var + 1e-5f);
  out[(size_t)row * C_ + t]       = f2bf((v0 - mu) * rstd * g[t] + bb[t]);
  out[(size_t)row * C_ + t + 256] = f2bf((v1 - mu) * rstd * g[t + 256] + bb[t + 256]);
  out[(size_t)row * C_ + t + 512] = f2bf((v2 - mu) * rstd * g[t + 512] + bb[t + 512]);
}

// ---------------- GEMM: C[M,N] = A[M,K] @ Bt[N,K]^T, fused epilogues ----------------
// R10: software-pipelined K-loop + bijective XCD swizzle. R11: LDS bank
// swizzle (conflicts 4.7M -> 0, timing-null at depth-1 -- regime gate).
// R12: prefetch depth 2 via 3-deep circular LDS buffers. Depth-1 gave each
// tile only ~1 compute phase (~300cy) to cover ~500-900cy load latency ->
// waves stalled at vmcnt(4) (MfmaUtil 20%). Now 2 stages (8 loads) stay in
// flight: steady-state s_waitcnt vmcnt(8); tile has ~2 phases to land.
// K/32 divisible by 3 for K in {768,3072} -> loop unrolled by 3, static
// buffer indices (rule #20). Buffer b is re-staged strictly after the
// end-barrier following COMPUTE(b) 3 steps earlier; in-flight writes always
// target a buffer distinct from the one being read (mod-3 separation).
#define MFMA16(d, a, b) d = __builtin_amdgcn_mfma_f32_16x16x32_bf16(a, b, d, 0, 0, 0)

template <int EPI>
__global__ void gemm_bt_k(const ushort_t* __restrict__ A,
                          const ushort_t* __restrict__ Bt,
                          const float* __restrict__ res,
                          void* __restrict__ outp,
                          int N, int K) {
  __shared__ __align__(16) ushort_t As[3][128][32];
  __shared__ __align__(16) ushort_t Bs[3][128][32];
  int t = threadIdx.x;

  // XCD-aware block swizzle (all launch grids are %8==0; guard anyway)
  int nwg = (int)(gridDim.x * gridDim.y);
  int orig = (int)(blockIdx.y * gridDim.x + blockIdx.x);
  int swz = (nwg & 7) ? orig : ((orig & 7) * (nwg >> 3) + (orig >> 3));
  int bx = swz % (int)gridDim.x, by = swz / (int)gridDim.x;
  int bn = bx * 128, bm = by * 128;

  int lane = t & 63, w = t >> 6;
  int wm = (w >> 1) * 64, wn = (w & 1) * 64;
  int lm = lane & 15;

  // staging: lane -> (row lr, phys chunk lane&3); source = logical chunk
  // (lane&3) ^ ((lr>>1)&3)  [lr>>1 == lane>>3]
  int lr = lane >> 2;
  int lc = (((lane & 3) ^ ((lane >> 3) & 3)) * 8);
  // read side: phys chunk = q ^ ((lm>>1)&3); lane bits 1-2 == lm bits 1-2
  int cx = (((lane >> 4) ^ ((lane >> 1) & 3)) * 8);

  const ushort_t* ga0 = A  + (size_t)(bm + w * 16 + lr) * K + lc;
  const ushort_t* gb0 = Bt + (size_t)(bn + w * 16 + lr) * K + lc;
  const size_t kstep64 = (size_t)64 * K;

  const f32x4 fz = {0.f, 0.f, 0.f, 0.f};
  f32x4 acc00 = fz, acc01 = fz, acc02 = fz, acc03 = fz;
  f32x4 acc10 = fz, acc11 = fz, acc12 = fz, acc13 = fz;
  f32x4 acc20 = fz, acc21 = fz, acc22 = fz, acc23 = fz;
  f32x4 acc30 = fz, acc31 = fz, acc32 = fz, acc33 = fz;

#define STAGE(BUF, TILE) do {                                   \
    int ko_ = (TILE) * 32;                                      \
    gload_lds16(ga0 + ko_, &As[BUF][w * 16][0]);                \
    gload_lds16(ga0 + kstep64 + ko_, &As[BUF][w * 16 + 64][0]); \
    gload_lds16(gb0 + ko_, &Bs[BUF][w * 16][0]);                \
    gload_lds16(gb0 + kstep64 + ko_, &Bs[BUF][w * 16 + 64][0]); \
  } while (0)

#define COMPUTE(BUF) do {                                            \
    bf16x8_t af0 = *(const bf16x8_t*)&As[BUF][wm + lm][cx];          \
    bf16x8_t af1 = *(const bf16x8_t*)&As[BUF][wm + 16 + lm][cx];     \
    bf16x8_t af2 = *(const bf16x8_t*)&As[BUF][wm + 32 + lm][cx];     \
    bf16x8_t af3 = *(const bf16x8_t*)&As[BUF][wm + 48 + lm][cx];     \
    bf16x8_t bg0 = *(const bf16x8_t*)&Bs[BUF][wn + lm][cx];          \
    bf16x8_t bg1 = *(const bf16x8_t*)&Bs[BUF][wn + 16 + lm][cx];     \
    bf16x8_t bg2 = *(const bf16x8_t*)&Bs[BUF][wn + 32 + lm][cx];     \
    bf16x8_t bg3 = *(const bf16x8_t*)&Bs[BUF][wn + 48 + lm][cx];     \
    MFMA16(acc00, af0, bg0); MFMA16(acc01, af0, bg1); MFMA16(acc02, af0, bg2); MFMA16(acc03, af0, bg3); \
    MFMA16(acc10, af1, bg0); MFMA16(acc11, af1, bg1); MFMA16(acc12, af1, bg2); MFMA16(acc13, af1, bg3); \
    MFMA16(acc20, af2, bg0); MFMA16(acc21, af2, bg1); MFMA16(acc22, af2, bg2); MFMA16(acc23, af2, bg3); \
    MFMA16(acc30, af3, bg0); MFMA16(acc31, af3, bg1); MFMA16(acc32, af3, bg2); MFMA16(acc33, af3, bg3); \
  } while (0)

  int nsteps = K >> 5;                 // K/32; 24 (K=768) or 96 (K=3072), %3==0
  STAGE(0, 0);
  STAGE(1, 1);
  for (int s = 0; s < nsteps; s += 3) {
    // --- sub 0: compute tile s (buf0), stage tile s+2 (buf2) ---
    STAGE(2, s + 2);                                   // s+2 <= nsteps-1 always
    asm volatile("s_waitcnt vmcnt(8)" ::: "memory");   // tile s landed; s+1,s+2 in flight
    __builtin_amdgcn_s_barrier();
    asm volatile("" ::: "memory");
    COMPUTE(0);
    asm volatile("" ::: "memory");
    __builtin_amdgcn_s_barrier();                      // buf0 reads done -> refillable
    // --- sub 1: compute tile s+1 (buf1), stage tile s+3 (buf0) ---
    if (s + 3 < nsteps) {
      STAGE(0, s + 3);
      asm volatile("s_waitcnt vmcnt(8)" ::: "memory"); // tile s+1 landed
    } else {
      asm volatile("s_waitcnt vmcnt(4)" ::: "memory"); // tail: s+1 landed, s+2 in flight
    }
    __builtin_amdgcn_s_barrier();
    asm volatile("" ::: "memory");
    COMPUTE(1);
    asm volatile("" ::: "memory");
    __builtin_amdgcn_s_barrier();                      // buf1 refillable
    // --- sub 2: compute tile s+2 (buf2), stage tile s+4 (buf1) ---
    if (s + 4 < nsteps) {
      STAGE(1, s + 4);
      asm volatile("s_waitcnt vmcnt(8)" ::: "memory"); // tile s+2 landed
    } else {
      asm volatile("s_waitcnt vmcnt(0)" ::: "memory"); // tail: drain
    }
    __builtin_amdgcn_s_barrier();
    asm volatile("" ::: "memory");
    COMPUTE(2);
    asm volatile("" ::: "memory");
    __builtin_amdgcn_s_barrier();                      // buf2 refillable
  }
#undef STAGE
#undef COMPUTE

  int rowb = bm + wm + (lane >> 4) * 4;
  int colb = bn + wn + lm;

#define ST(vv, row, jj) do { \
    float v = (vv); \
    size_t idx = (size_t)(row) * N + colb + (jj) * 16; \
    if constexpr (EPI == 0) { ((ushort_t*)outp)[idx] = f2bf(v); } \
    else if constexpr (EPI == 1) { ((float*)outp)[idx] = v + res[idx]; } \
    else { float gl = 0.5f * v * (1.0f + erff(v * 0.70710678118654752f)); \
           ((ushort_t*)outp)[idx] = f2bf(gl); } \
  } while (0)
#define STROW(a0, a1, a2, a3, row, rr) \
    ST(a0[rr], row, 0); ST(a1[rr], row, 1); ST(a2[rr], row, 2); ST(a3[rr], row, 3);
#define STBLK(a0, a1, a2, a3, rbase) \
    STROW(a0, a1, a2, a3, (rbase), 0) STROW(a0, a1, a2, a3, (rbase) + 1, 1) \
    STROW(a0, a1, a2, a3, (rbase) + 2, 2) STROW(a0, a1, a2, a3, (rbase) + 3, 3)

  STBLK(acc00, acc01, acc02, acc03, rowb)
  STBLK(acc10, acc11, acc12, acc13, rowb + 16)
  STBLK(acc20, acc21, acc22, acc23, rowb + 32)
  STBLK(acc30, acc31, acc32, acc33, rowb + 48)
#undef ST
#undef STROW
#undef STBLK
}

// ---------------- flash attention (causal) ----------------
// R9: cooperative LDS staging of K/V tiles (all 4 waves share the same tiles).
// Double-buffered global_load_lds with counted s_waitcnt vmcnt(4) + raw
// s_barrier so the next tile's loads stay in flight across the barrier.
// XOR-swizzle applied on BOTH sides (pre-swizzled global source + swizzled
// ds_read). LDS 41KB -> 3 blocks/CU.
__device__ __forceinline__ void stage64(const ushort_t* __restrict__ g, size_t strideE,
                                        ushort_t* l, int w, int lane) {
  // stage 16 rows (w*16..w*16+15) of a 64x64 bf16 tile: 2 x 1KB gload_lds
  int rl = lane >> 3;                        // local row 0..7 within 8-row slab
  int ce = ((lane & 7) ^ rl) << 3;           // pre-swizzled element col (8-elem chunks)
  const ushort_t* g0 = g + (size_t)(w * 16 + rl) * strideE + ce;
  gload_lds16(g0, l + (size_t)(w * 16) * 64);
  const ushort_t* g1 = g + (size_t)(w * 16 + 8 + rl) * strideE + ce;
  gload_lds16(g1, l + (size_t)(w * 16 + 8) * 64);
}

__global__ __launch_bounds__(256, 3) void attn_k(const ushort_t* __restrict__ qkv,
                                                 const ushort_t* __restrict__ vg,
                                                 ushort_t* __restrict__ y) {
  __shared__ __align__(16) ushort_t Ks[2][64][64];   // [buf][t_local][d] swizzled
  __shared__ __align__(16) ushort_t Vs[2][64][64];   // [buf][d][t_local] swizzled
  __shared__ __align__(16) ushort_t Ps[4][16][72];

  int t = threadIdx.x;
  int w = t >> 6, lane = t & 63;
  int lm = lane & 15, qq = lane >> 4, q8 = qq * 8;
  int bh = blockIdx.x;
  int qt = (int)gridDim.y - 1 - (int)blockIdx.y;   // heavy q-tiles dispatch first
  int b = bh / H_, h = bh % H_;

  size_t baserow = (size_t)b * T_;
  const ushort_t* qkvb = qkv + baserow * C3_ + h * D_;
  const ushort_t* kbase = qkvb + C_;
  const ushort_t* vbase = vg + (size_t)bh * D_ * T_;

  int qrow0 = qt * 64 + w * 16;   // this wave's 16 q rows
  const ushort_t* qp = qkvb + (size_t)(qrow0 + lm) * C3_ + q8;
  bf16x8_t aq0 = *(const bf16x8_t*)(qp);
  bf16x8_t aq1 = *(const bf16x8_t*)(qp + 32);
  __builtin_amdgcn_s_waitcnt(0);   // drain Q loads so in-loop vmcnt counting is exact

  const f32x4 fz = {0.f, 0.f, 0.f, 0.f};
  f32x4 aO0 = fz, aO1 = fz, aO2 = fz, aO3 = fz;
  f32x4 lsum = fz;                 // per-lane partial softmax denominators

  const float SC = 0.125f * 1.44269504088896340736f;  // scale * log2(e)

#define BODY(CUR, KT, MASKED)                                                   \
  {                                                                             \
    const char* Kb = (const char*)&Ks[CUR][0][0];                               \
    const char* Vb = (const char*)&Vs[CUR][0][0];                               \
    const int rsw = (lm & 7) << 4;                                              \
    const int c0 = (qq * 16) ^ rsw;                                             \
    const int c1 = (64 + qq * 16) ^ rsw;                                        \
    bf16x8_t kf[8], vv[8];                                                      \
    _Pragma("unroll") for (int j = 0; j < 4; j++) {                             \
      int rb = (j * 16 + lm) << 7;                                              \
      kf[2*j]   = *(const bf16x8_t*)(Kb + rb + c0);                             \
      kf[2*j+1] = *(const bf16x8_t*)(Kb + rb + c1);                             \
      vv[2*j]   = *(const bf16x8_t*)(Vb + rb + c0);                             \
      vv[2*j+1] = *(const bf16x8_t*)(Vb + rb + c1);                             \
    }                                                                           \
    f32x4 sa0 = fz, sa1 = fz, sa2 = fz, sa3 = fz;                               \
    MFMA16(sa0, aq0, kf[0]); MFMA16(sa0, aq1, kf[1]);                           \
    MFMA16(sa1, aq0, kf[2]); MFMA16(sa1, aq1, kf[3]);                           \
    MFMA16(sa2, aq0, kf[4]); MFMA16(sa2, aq1, kf[5]);                           \
    MFMA16(sa3, aq0, kf[6]); MFMA16(sa3, aq1, kf[7]);                           \
    _Pragma("unroll") for (int j = 0; j < 4; j++) {                             \
      f32x4 sj = (j == 0) ? sa0 : (j == 1) ? sa1 : (j == 2) ? sa2 : sa3;        \
      _Pragma("unroll") for (int r2 = 0; r2 < 4; r2++) {                        \
        float v = sj[r2] * SC;                                                  \
        if (MASKED && (j * 16 + lm) > (w * 16 + qq * 4 + r2)) v = -1e30f;       \
        float p = exp2f(v);                                                     \
        lsum[r2] += p;                                                          \
        Ps[w][qq * 4 + r2][j * 16 + lm] = f2bf_trunc(p);                        \
      }                                                                         \
    }                                                                           \
    {                                                                           \
      bf16x8_t ap_lo = *(const bf16x8_t*)&Ps[w][lm][q8];                        \
      bf16x8_t ap_hi = *(const bf16x8_t*)&Ps[w][lm][32 + q8];                   \
      MFMA16(aO0, ap_lo, vv[0]); MFMA16(aO0, ap_hi, vv[1]);                     \
      MFMA16(aO1, ap_lo, vv[2]); MFMA16(aO1, ap_hi, vv[3]);                     \
      MFMA16(aO2, ap_lo, vv[4]); MFMA16(aO2, ap_hi, vv[5]);                     \
      MFMA16(aO3, ap_lo, vv[6]); MFMA16(aO3, ap_hi, vv[7]);                     \
    }                                                                           \
  }

  // prologue: stage tile 0 into buffer 0 (4 async loads per wave)
  stage64(kbase, C3_, &Ks[0][0][0], w, lane);
  stage64(vbase, T_, &Vs[0][0][0], w, lane);
  int cur = 0;
  for (int kt = 0; kt <= qt; ++kt) {
    if (kt < qt) {
      // issue next tile's loads into the other buffer, keep them in flight
      stage64(kbase + (size_t)(kt + 1) * 64 * C3_, C3_, &Ks[cur ^ 1][0][0], w, lane);
      stage64(vbase + (size_t)(kt + 1) * 64,       T_,  &Vs[cur ^ 1][0][0], w, lane);
      asm volatile("s_waitcnt vmcnt(4)" ::: "memory");  // tile kt landed; kt+1 in flight
    } else {
      asm volatile("s_waitcnt vmcnt(0)" ::: "memory");  // last tile: drain
    }
    __builtin_amdgcn_s_barrier();      // all waves' tile-kt data visible
    asm volatile("" ::: "memory");     // fence: no LDS reads hoisted above barrier
    if (kt == qt) { BODY(cur, kt, true) }
    else          { BODY(cur, kt, false) }
    asm volatile("" ::: "memory");     // fence: reads done before buffer reuse
    __builtin_amdgcn_s_barrier();      // safe to overwrite buffer cur next iter
    cur ^= 1;
  }
#undef BODY

#pragma unroll
  for (int r2 = 0; r2 < 4; r2++) {
    float s = lsum[r2];
    s += __shfl_xor(s, 1);
    s += __shfl_xor(s, 2);
    s += __shfl_xor(s, 4);
    s += __shfl_xor(s, 8);
    float inv = 1.f / s;
    size_t orow = (baserow + qrow0 + qq * 4 + r2) * C_ + h * D_;
    y[orow + lm]      = f2bf(aO0[r2] * inv);
    y[orow + 16 + lm] = f2bf(aO1[r2] * inv);
    y[orow + 32 + lm] = f2bf(aO2[r2] * inv);
    y[orow + 48 + lm] = f2bf(aO3[r2] * inv);
  }
}

extern "C" void kernel_launch(void* const* d_in, const int* in_sizes, int n_in,
                              void* d_out, int out_size, void* d_ws, size_t ws_size,
                              hipStream_t stream) {
  (void)in_sizes; (void)n_in; (void)out_size; (void)ws_size;
  const float* x      = (const float*)d_in[0];
  const float* ln1_g  = (const float*)d_in[1];
  const float* ln1_b  = (const float*)d_in[2];
  const float* W_attn = (const float*)d_in[3];
  const float* W_o    = (const float*)d_in[4];
  const float* ln2_g  = (const float*)d_in[5];
  const float* ln2_b  = (const float*)d_in[6];
  const float* W_fc   = (const float*)d_in[7];
  const float* W_proj = (const float*)d_in[8];

  char* ws = (char*)d_ws;
  ushort_t* big  = (ushort_t*)(ws);
  ushort_t* Vg   = (ushort_t*)(ws + 37748736);  // V^T [48][64][2048] bf16; dead before h is written
  ushort_t* tmp  = (ushort_t*)(ws + 50331648);  // xhat1 / y / xhat2 (8192x768 bf16)
  float*    x2   = (float*)   (ws + 62914560);  // residual1 fp32 (8192x768)
  ushort_t* Wat  = (ushort_t*)(ws + 88080384);  // W_attn^T [2304,768] bf16
  ushort_t* Wot  = (ushort_t*)(ws + 91619328);  // W_o^T    [768,768]  bf16
  ushort_t* Wfct = (ushort_t*)(ws + 92798976);  // W_fc^T   [3072,768] bf16
  ushort_t* Wpt  = (ushort_t*)(ws + 97517568);  // W_proj^T [768,3072] bf16

  dim3 tb(32, 8);
  transpose_k<<<dim3(C3_ / 32, C_ / 32), tb, 0, stream>>>(W_attn, Wat, C_, C3_);
  transpose_k<<<dim3(C_ / 32, C_ / 32), tb, 0, stream>>>(W_o, Wot, C_, C_);
  transpose_k<<<dim3(HID_ / 32, C_ / 32), tb, 0, stream>>>(W_fc, Wfct, C_, HID_);
  transpose_k<<<dim3(C_ / 32, HID_ / 32), tb, 0, stream>>>(W_proj, Wpt, HID_, C_);

  ln_k<<<M_, 256, 0, stream>>>(x, ln1_g, ln1_b, tmp);
  gemm_bt_k<0><<<dim3(C3_ / 128, M_ / 128), 256, 0, stream>>>(tmp, Wat, nullptr, big, C3_, C_);
  vtrans_k<<<dim3(T_ / 32, D_ / 32, B_ * H_), tb, 0, stream>>>(big, Vg);
  attn_k<<<dim3(B_ * H_, T_ / 64), 256, 0, stream>>>(big, Vg, tmp);
  gemm_bt_k<1><<<dim3(C_ / 128, M_ / 128), 256, 0, stream>>>(tmp, Wot, x, x2, C_, C_);
  ln_k<<<M_, 256, 0, stream>>>(x2, ln2_g, ln2_b, tmp);
  gemm_bt_k<2><<<dim3(HID_ / 128, M_ / 128), 256, 0, stream>>>(tmp, Wfct, nullptr, big, HID_, C_);
  gemm_bt_k<1><<<dim3(C_ / 128, M_ / 128), 256, 0, stream>>>(big, Wpt, x2, d_out, C_, HID_);
}